// Round 5
// baseline (275.647 us; speedup 1.0000x reference)
//
#include <hip/hip_runtime.h>

// AWQ int4 GEMM: out[M,N] = x[M,K] @ dequant(qweight,qzeros,scales)
// M=2048 K=4096 N=11008 G=128.
// f16 MFMA, 128x128 tile, 4 waves, BK=64, DOUBLE-BUFFERED single-barrier loop:
//   gload_lds A(t+1) + load Braw(t+1) -> MFMA(t) [setprio] -> dequant+write B(t+1) -> barrier.
// A path: x pre-converted to f16 pre-swizzled LDS images in d_ws.

#define MDIM 2048
#define KDIM 4096
#define NDIM 11008
#define NPC  1376          // N/8 packed columns
#define BM 128
#define BN 128
#define BK 64
#define NT (KDIM / BK)     // 64

typedef _Float16 half8   __attribute__((ext_vector_type(8)));
typedef _Float16 half2v  __attribute__((ext_vector_type(2)));
typedef __fp16   fp16x2n __attribute__((ext_vector_type(2)));
typedef float    f32x4   __attribute__((ext_vector_type(4)));

__device__ __forceinline__ half2v u2h(unsigned u) { union { unsigned u; half2v h; } v; v.u = u; return v.h; }
__device__ __forceinline__ unsigned h2u(half2v h) { union { unsigned u; half2v h; } v; v.h = h; return v.u; }
__device__ __forceinline__ unsigned pkrtz(float a, float b) {
    union { fp16x2n h; unsigned u; } v;
    v.h = __builtin_amdgcn_cvt_pkrtz(a, b);
    return v.u;
}

// ---- pre-kernel: x fp32 -> f16 tile-images (pre-swizzled LDS layout) ----
// image per (mb,kt): [r 0..127][slot' = s^(r&7)][8 half] = 16KB
__global__ __launch_bounds__(256) void xconv(const float* __restrict__ x,
                                             _Float16* __restrict__ xi) {
    const int id = blockIdx.x * 256 + threadIdx.x;   // 2^20 total
    const int s  = id & 7;
    const int r  = (id >> 3) & 127;
    const int kt = (id >> 10) & 63;
    const int mb = id >> 16;                          // 0..15
    const float* src = x + (size_t)(mb * 128 + r) * KDIM + kt * 64 + s * 8;
    const float4 f0 = *(const float4*)src;
    const float4 f1 = *(const float4*)(src + 4);
    half8 h;
    h[0] = (_Float16)f0.x; h[1] = (_Float16)f0.y; h[2] = (_Float16)f0.z; h[3] = (_Float16)f0.w;
    h[4] = (_Float16)f1.x; h[5] = (_Float16)f1.y; h[6] = (_Float16)f1.z; h[7] = (_Float16)f1.w;
    const size_t off = ((size_t)(mb * 64 + kt) * 128 + r) * 64 + (size_t)((s ^ (r & 7)) * 8);
    *(half8*)(xi + off) = h;
}

__global__ __launch_bounds__(256, 2)
void awq_gemm(const _Float16* __restrict__ xi,
              const int* __restrict__ qw,
              const unsigned* __restrict__ qz,
              const float* __restrict__ sc,
              float* __restrict__ out)
{
    // double-buffered tiles, 16KB each: [row/n][granule^swz][8 half]
    __shared__ _Float16 As0[BM * BK], As1[BM * BK];
    __shared__ _Float16 Bs0[BN * BK], Bs1[BN * BK];

    const int t    = threadIdx.x;
    const int lane = t & 63;
    const int wave = t >> 6;           // 0..3
    const int WR   = wave >> 1;        // 0..1
    const int WC   = wave & 1;         // 0..1

    const int mb  = blockIdx.y;
    const int m0  = mb * BM;
    const int n0  = blockIdx.x * BN;
    const int pc0 = n0 >> 3;

    // B staging: thread -> (packed col pc 0..15, k-quad kq 0..15)
    const int pc  = t & 15;
    const int kq  = t >> 4;
    const int pcg = pc0 + pc;

    f32x4 acc[4][4];
    #pragma unroll
    for (int i = 0; i < 4; ++i)
        #pragma unroll
        for (int j = 0; j < 4; ++j)
            acc[i][j] = (f32x4){0.f, 0.f, 0.f, 0.f};

    unsigned rw0_, rw1_, rw2_, rw3_, rz_;
    float4   rs0_, rs1_;

#define LOADB(TT) do {                                                        \
    const int* bp = qw + ((size_t)(TT) * BK + kq * 4) * NPC + pcg;            \
    rw0_ = (unsigned)bp[0];       rw1_ = (unsigned)bp[NPC];                   \
    rw2_ = (unsigned)bp[2 * NPC]; rw3_ = (unsigned)bp[3 * NPC];               \
    rz_  = qz[(size_t)((TT) >> 1) * NPC + pcg];                               \
    const float* sp = sc + (size_t)((TT) >> 1) * NDIM + n0 + pc * 8;          \
    rs0_ = *(const float4*)sp; rs1_ = *(const float4*)(sp + 4);               \
} while (0)

#define AGLOAD(TT, dstBase) do {                                              \
    const _Float16* img = xi + (size_t)(mb * NT + (TT)) * 8192;               \
    _Pragma("unroll")                                                         \
    for (int c = 0; c < 4; ++c) {                                             \
        __builtin_amdgcn_global_load_lds(                                     \
            (const __attribute__((address_space(1))) void*)                   \
                (img + wave * 512 + c * 2048 + lane * 8),                     \
            (__attribute__((address_space(3))) void*)                         \
                ((char*)(dstBase) + wave * 1024 + c * 4096),                  \
            16, 0, 0);                                                        \
    }                                                                         \
} while (0)

#define DEQWRITE(dstBase) do {                                                \
    const int kslot = kq >> 1;                                                \
    const int ksub  = (kq & 1) * 8;                                           \
    const unsigned M_ = 0x000F000Fu, G_ = 0x64006400u;                        \
    _Pragma("unroll")                                                         \
    for (int p = 0; p < 4; ++p) {                                             \
        const unsigned zp = ((rz_ >> (4 * p)) & M_) | G_;                     \
        const unsigned sp_ = (p == 0) ? pkrtz(rs0_.x, rs0_.y)                 \
                          : (p == 1) ? pkrtz(rs0_.z, rs0_.w)                  \
                          : (p == 2) ? pkrtz(rs1_.x, rs1_.y)                  \
                                     : pkrtz(rs1_.z, rs1_.w);                 \
        const unsigned d0 = h2u((u2h(((rw0_ >> (4*p)) & M_) | G_) - u2h(zp)) * u2h(sp_)); \
        const unsigned d1 = h2u((u2h(((rw1_ >> (4*p)) & M_) | G_) - u2h(zp)) * u2h(sp_)); \
        const unsigned d2 = h2u((u2h(((rw2_ >> (4*p)) & M_) | G_) - u2h(zp)) * u2h(sp_)); \
        const unsigned d3 = h2u((u2h(((rw3_ >> (4*p)) & M_) | G_) - u2h(zp)) * u2h(sp_)); \
        const int ne = pc * 8 + 2 * p, no = ne + 1;                           \
        const int swe = (ne & 7) ^ ((ne >> 3) & 7);                           \
        const int swo = (no & 7) ^ ((no >> 3) & 7);                           \
        uint2 ev, od;                                                         \
        ev.x = __builtin_amdgcn_perm(d1, d0, 0x05040100u);                    \
        ev.y = __builtin_amdgcn_perm(d3, d2, 0x05040100u);                    \
        od.x = __builtin_amdgcn_perm(d1, d0, 0x07060302u);                    \
        od.y = __builtin_amdgcn_perm(d3, d2, 0x07060302u);                    \
        *(uint2*)((char*)(dstBase) + ne * 128 + ((kslot ^ swe) * 16) + ksub) = ev; \
        *(uint2*)((char*)(dstBase) + no * 128 + ((kslot ^ swo) * 16) + ksub) = od; \
    }                                                                         \
} while (0)

#define COMPUTE(Ab, Bb) do {                                                  \
    _Pragma("unroll")                                                         \
    for (int ks = 0; ks < 2; ++ks) {                                          \
        const int slot = ks * 4 + (lane >> 4);                                \
        half8 bfr[4];                                                         \
        _Pragma("unroll")                                                     \
        for (int j = 0; j < 4; ++j) {                                         \
            const int n  = WC * 64 + j * 16 + (lane & 15);                    \
            const int sw = (n & 7) ^ ((n >> 3) & 7);                          \
            bfr[j] = *(const half8*)((char*)(Bb) + n * 128 + ((slot ^ sw) * 16)); \
        }                                                                     \
        __builtin_amdgcn_s_setprio(1);                                        \
        _Pragma("unroll")                                                     \
        for (int i = 0; i < 4; ++i) {                                         \
            const int row = WR * 64 + i * 16 + (lane & 15);                   \
            const half8 af = *(const half8*)((char*)(Ab) + row * 128 + ((slot ^ (row & 7)) * 16)); \
            _Pragma("unroll")                                                 \
            for (int j = 0; j < 4; ++j)                                       \
                acc[i][j] = __builtin_amdgcn_mfma_f32_16x16x32_f16(           \
                    af, bfr[j], acc[i][j], 0, 0, 0);                          \
        }                                                                     \
        __builtin_amdgcn_s_setprio(0);                                        \
    }                                                                         \
} while (0)

    // ---- prologue: stage tile 0 into buffer 0 ----
    AGLOAD(0, As0);
    LOADB(0);
    DEQWRITE(Bs0);
    __syncthreads();

    _Float16 *Acur = As0, *Anxt = As1, *Bcur = Bs0, *Bnxt = Bs1;

    for (int tt = 0; tt < NT; ++tt) {
        if (tt + 1 < NT) {
            AGLOAD(tt + 1, Anxt);     // issued first: full tile to complete
            LOADB(tt + 1);            // raw B for next tile -> regs
        }
        COMPUTE(Acur, Bcur);          // 32 MFMA under setprio
        if (tt + 1 < NT) {
            DEQWRITE(Bnxt);           // VALU in the MFMA shadow of other waves
        }
        __syncthreads();              // vmcnt(0)+lgkmcnt(0)+barrier: publish buf^1
        _Float16* tp;
        tp = Acur; Acur = Anxt; Anxt = tp;
        tp = Bcur; Bcur = Bnxt; Bnxt = tp;
    }

    // ---- epilogue: C/D layout col=lane&15, row=(lane>>4)*4+e ----
    const int crow = (lane >> 4) * 4;
    const int ccol = lane & 15;
    #pragma unroll
    for (int i = 0; i < 4; ++i) {
        #pragma unroll
        for (int j = 0; j < 4; ++j) {
            const size_t base =
                (size_t)(m0 + WR * 64 + i * 16 + crow) * NDIM +
                (n0 + WC * 64 + j * 16 + ccol);
            #pragma unroll
            for (int e = 0; e < 4; ++e)
                out[base + (size_t)e * NDIM] = acc[i][j][e];
        }
    }
#undef LOADB
#undef AGLOAD
#undef DEQWRITE
#undef COMPUTE
}

extern "C" void kernel_launch(void* const* d_in, const int* in_sizes, int n_in,
                              void* d_out, int out_size, void* d_ws, size_t ws_size,
                              hipStream_t stream) {
    const float*    x  = (const float*)d_in[0];
    const int*      qw = (const int*)d_in[1];
    const unsigned* qz = (const unsigned*)d_in[2];
    const float*    sc = (const float*)d_in[3];
    float* out = (float*)d_out;

    if (ws_size < (size_t)MDIM * KDIM * 2) return;   // proven to fit (round 4)

    _Float16* xi = (_Float16*)d_ws;
    xconv<<<4096, 256, 0, stream>>>(x, xi);

    dim3 grid(NDIM / BN, MDIM / BM);   // 86 x 16
    awq_gemm<<<grid, 256, 0, stream>>>(xi, qw, qz, sc, out);
}

// Round 6
// 245.794 us; speedup vs baseline: 1.1215x; 1.1215x over previous
//
#include <hip/hip_runtime.h>

// AWQ int4 GEMM: out[M,N] = x[M,K] @ dequant(qweight,qzeros,scales)
// M=2048 K=4096 N=11008 G=128.
// TWO-PASS: (1) x fp32->f16 tile images; (2) W int4->f16 dequant ONCE into
// pre-swizzled tile images; (3) pure gload_lds double-buffered f16 MFMA GEMM.
// Fallback to round-4 fused kernel if ws too small.

#define MDIM 2048
#define KDIM 4096
#define NDIM 11008
#define NPC  1376          // N/8 packed columns
#define NT   64            // K / 64

typedef _Float16 half8   __attribute__((ext_vector_type(8)));
typedef _Float16 half2v  __attribute__((ext_vector_type(2)));
typedef __fp16   fp16x2n __attribute__((ext_vector_type(2)));
typedef float    f32x4   __attribute__((ext_vector_type(4)));

__device__ __forceinline__ half2v u2h(unsigned u) { union { unsigned u; half2v h; } v; v.u = u; return v.h; }
__device__ __forceinline__ unsigned h2u(half2v h) { union { unsigned u; half2v h; } v; v.h = h; return v.u; }
__device__ __forceinline__ unsigned pkrtz(float a, float b) {
    union { fp16x2n h; unsigned u; } v;
    v.h = __builtin_amdgcn_cvt_pkrtz(a, b);
    return v.u;
}

// ============ pass 1: x fp32 -> f16 images, 128-row tiles ============
// image per (mb 0..15, kt 0..63): [r 0..127][slot' = s^(r&7)][8 half] = 16KB
__global__ __launch_bounds__(256) void xconv128(const float* __restrict__ x,
                                                _Float16* __restrict__ xi) {
    const int id = blockIdx.x * 256 + threadIdx.x;   // 2^20
    const int s  = id & 7;
    const int r  = (id >> 3) & 127;
    const int kt = (id >> 10) & 63;
    const int mb = id >> 16;
    const float* src = x + (size_t)(mb * 128 + r) * KDIM + kt * 64 + s * 8;
    const float4 f0 = *(const float4*)src;
    const float4 f1 = *(const float4*)(src + 4);
    uint4 w;
    w.x = pkrtz(f0.x, f0.y); w.y = pkrtz(f0.z, f0.w);
    w.z = pkrtz(f1.x, f1.y); w.w = pkrtz(f1.z, f1.w);
    const size_t off = ((size_t)(mb * 64 + kt) * 128 + r) * 64 + (size_t)((s ^ (r & 7)) * 8);
    *(uint4*)(xi + off) = w;
}

// ============ pass 2: W dequant ONCE -> f16 images ============
// image per (nb 0..85, kt 0..63): [n 0..127][slot' = s^swz(n)][8 half] = 16KB,
// swz(n) = (n&7)^((n>>3)&7). Block = 16 pc x 16 kb -> builds 2 images in LDS,
// then coalesced copy-out.
__global__ __launch_bounds__(256)
void wdeq(const int* __restrict__ qw, const unsigned* __restrict__ qz,
          const float* __restrict__ sc, _Float16* __restrict__ wi)
{
    __shared__ _Float16 img[2 * 8192];   // 32KB = 2 images

    const int t   = threadIdx.x;
    const int pcL = t & 15;
    const int kbL = t >> 4;
    const int nb  = blockIdx.x;          // 0..85
    const int by  = blockIdx.y;          // 0..31 (= group g)
    const int pcg = nb * 16 + pcL;
    const int kb  = by * 16 + kbL;       // k-octet, k0 = kb*8

    const int* qp = qw + (size_t)(kb * 8) * NPC + pcg;
    unsigned w[8];
    #pragma unroll
    for (int r = 0; r < 8; ++r) w[r] = (unsigned)qp[(size_t)r * NPC];
    const unsigned rz = qz[(size_t)by * NPC + pcg];
    const float* sp = sc + (size_t)by * NDIM + pcg * 8;
    const float4 rs0 = *(const float4*)sp;
    const float4 rs1 = *(const float4*)(sp + 4);

    const int kt2 = kbL >> 3;            // which of the 2 LDS images
    const int s   = kbL & 7;             // k-slot in image
    const unsigned M_ = 0x000F000Fu, G_ = 0x64006400u;

    #pragma unroll
    for (int p = 0; p < 4; ++p) {        // n-pair (2p, 2p+1)
        const unsigned zp  = ((rz >> (4 * p)) & M_) | G_;
        const unsigned spk = (p == 0) ? pkrtz(rs0.x, rs0.y)
                           : (p == 1) ? pkrtz(rs0.z, rs0.w)
                           : (p == 2) ? pkrtz(rs1.x, rs1.y)
                                      : pkrtz(rs1.z, rs1.w);
        unsigned d[8];
        #pragma unroll
        for (int r = 0; r < 8; ++r)
            d[r] = h2u((u2h(((w[r] >> (4 * p)) & M_) | G_) - u2h(zp)) * u2h(spk));
        uint4 ev, od;
        ev.x = __builtin_amdgcn_perm(d[1], d[0], 0x05040100u);
        ev.y = __builtin_amdgcn_perm(d[3], d[2], 0x05040100u);
        ev.z = __builtin_amdgcn_perm(d[5], d[4], 0x05040100u);
        ev.w = __builtin_amdgcn_perm(d[7], d[6], 0x05040100u);
        od.x = __builtin_amdgcn_perm(d[1], d[0], 0x07060302u);
        od.y = __builtin_amdgcn_perm(d[3], d[2], 0x07060302u);
        od.z = __builtin_amdgcn_perm(d[5], d[4], 0x07060302u);
        od.w = __builtin_amdgcn_perm(d[7], d[6], 0x07060302u);
        const int ne = pcL * 8 + 2 * p, no = ne + 1;
        const int swe = (ne & 7) ^ ((ne >> 3) & 7);
        const int swo = (no & 7) ^ ((no >> 3) & 7);
        *(uint4*)((char*)img + kt2 * 16384 + ne * 128 + ((s ^ swe) * 16)) = ev;
        *(uint4*)((char*)img + kt2 * 16384 + no * 128 + ((s ^ swo) * 16)) = od;
    }
    __syncthreads();

    // coalesced copy-out: 2 images = 32KB
    _Float16* dst = wi + (size_t)(nb * 64 + by * 2) * 8192;
    #pragma unroll
    for (int i = 0; i < 8; ++i) {
        const int idx = i * 256 + t;
        *(uint4*)((char*)dst + idx * 16) = *(const uint4*)((const char*)img + idx * 16);
    }
}

// ============ pass 3: pure gload_lds double-buffered GEMM ============
// 128x128 tile, BK=64, 4 waves, dbuf 64KB, ONE barrier per tile.
__global__ __launch_bounds__(256, 2)
void awq_gemm2(const _Float16* __restrict__ xi,
               const _Float16* __restrict__ wi,
               float* __restrict__ out)
{
    __shared__ _Float16 As[2][128 * 64];   // 16KB each
    __shared__ _Float16 Bs[2][128 * 64];

    const int t    = threadIdx.x;
    const int lane = t & 63;
    const int wave = t >> 6;
    const int WR   = wave >> 1;
    const int WC   = wave & 1;

    const int mb = blockIdx.x;     // 0..15 (fast axis: consecutive blocks share W panel)
    const int nb = blockIdx.y;     // 0..85
    const int m0 = mb * 128;
    const int n0 = nb * 128;

    f32x4 acc[4][4];
    #pragma unroll
    for (int i = 0; i < 4; ++i)
        #pragma unroll
        for (int j = 0; j < 4; ++j)
            acc[i][j] = (f32x4){0.f, 0.f, 0.f, 0.f};

#define GLOAD2(img, dstBase) do {                                             \
    _Pragma("unroll")                                                         \
    for (int c = 0; c < 4; ++c) {                                             \
        __builtin_amdgcn_global_load_lds(                                     \
            (const __attribute__((address_space(1))) void*)                   \
                ((img) + c * 2048 + wave * 512 + lane * 8),                   \
            (__attribute__((address_space(3))) void*)                         \
                ((char*)(dstBase) + c * 4096 + wave * 1024),                  \
            16, 0, 0);                                                        \
    }                                                                         \
} while (0)

#define COMPUTE(Ab, Bb) do {                                                  \
    _Pragma("unroll")                                                         \
    for (int ks = 0; ks < 2; ++ks) {                                          \
        const int slot = ks * 4 + (lane >> 4);                                \
        half8 bfr[4];                                                         \
        _Pragma("unroll")                                                     \
        for (int j = 0; j < 4; ++j) {                                         \
            const int n  = WC * 64 + j * 16 + (lane & 15);                    \
            const int sw = (n & 7) ^ ((n >> 3) & 7);                          \
            bfr[j] = *(const half8*)((const char*)(Bb) + n * 128 + ((slot ^ sw) * 16)); \
        }                                                                     \
        _Pragma("unroll")                                                     \
        for (int i = 0; i < 4; ++i) {                                         \
            const int row = WR * 64 + i * 16 + (lane & 15);                   \
            const half8 af = *(const half8*)((const char*)(Ab) + row * 128 + ((slot ^ (row & 7)) * 16)); \
            _Pragma("unroll")                                                 \
            for (int j = 0; j < 4; ++j)                                       \
                acc[i][j] = __builtin_amdgcn_mfma_f32_16x16x32_f16(           \
                    af, bfr[j], acc[i][j], 0, 0, 0);                          \
        }                                                                     \
    }                                                                         \
} while (0)

    const _Float16* aimg = xi + (size_t)mb * NT * 8192;
    const _Float16* bimg = wi + (size_t)nb * NT * 8192;

    GLOAD2(aimg, As[0]);
    GLOAD2(bimg, Bs[0]);
    __syncthreads();                       // vmcnt(0): tile 0 resident

    int cur = 0;
    for (int tt = 0; tt < NT; ++tt) {
        const int nx = cur ^ 1;
        if (tt + 1 < NT) {                 // prefetch BEFORE compute
            GLOAD2(aimg + (size_t)(tt + 1) * 8192, As[nx]);
            GLOAD2(bimg + (size_t)(tt + 1) * 8192, Bs[nx]);
        }
        COMPUTE(As[cur], Bs[cur]);
        __syncthreads();                   // drain prefetch + publish
        cur = nx;
    }

    const int crow = (lane >> 4) * 4;
    const int ccol = lane & 15;
    #pragma unroll
    for (int i = 0; i < 4; ++i) {
        #pragma unroll
        for (int j = 0; j < 4; ++j) {
            const size_t base =
                (size_t)(m0 + WR * 64 + i * 16 + crow) * NDIM +
                (n0 + WC * 64 + j * 16 + ccol);
            #pragma unroll
            for (int e = 0; e < 4; ++e)
                out[base + (size_t)e * NDIM] = acc[i][j][e];
        }
    }
#undef GLOAD2
#undef COMPUTE
}

// ============ FALLBACK: round-4 proven pipeline (fused dequant) ============
__global__ __launch_bounds__(256) void xconv256(const float* __restrict__ x,
                                                _Float16* __restrict__ xi) {
    const int id = blockIdx.x * 256 + threadIdx.x;
    const int s  = id & 7;
    const int r  = (id >> 3) & 255;
    const int kt = (id >> 11) & 63;
    const int mb = id >> 17;
    const float* src = x + (size_t)(mb * 256 + r) * KDIM + kt * 64 + s * 8;
    const float4 f0 = *(const float4*)src;
    const float4 f1 = *(const float4*)(src + 4);
    uint4 w;
    w.x = pkrtz(f0.x, f0.y); w.y = pkrtz(f0.z, f0.w);
    w.z = pkrtz(f1.x, f1.y); w.w = pkrtz(f1.z, f1.w);
    const size_t off = ((size_t)(mb * 64 + kt) * 256 + r) * 64 + (size_t)((s ^ (r & 7)) * 8);
    *(uint4*)(xi + off) = w;
}

template <bool XWS>
__global__ __launch_bounds__(512, 4)
void awq_fused(const float* __restrict__ x,
               const _Float16* __restrict__ xi,
               const int* __restrict__ qw,
               const unsigned* __restrict__ qz,
               const float* __restrict__ sc,
               float* __restrict__ out)
{
    __shared__ _Float16 As[256 * 64];
    __shared__ _Float16 Bs[128 * 64];

    const int t    = threadIdx.x;
    const int lane = t & 63;
    const int wave = t >> 6;
    const int WR   = wave >> 1;
    const int WC   = wave & 1;

    const int mb  = blockIdx.y;
    const int m0  = mb * 256;
    const int n0  = blockIdx.x * 128;
    const int pc0 = n0 >> 3;

    const int bpc = t & 15;
    const int bkp = t >> 4;
    const int*      qwp = qw + (size_t)(2 * bkp) * NPC + pc0 + bpc;
    const unsigned* qzp = qz + pc0 + bpc;
    const float*    scp = sc + n0 + bpc * 8;

    const int ar = t >> 1;
    const int ak = (t & 1) * 32;
    const float* xp = x + (size_t)(m0 + ar) * KDIM + ak;

    f32x4 acc[4][4];
    #pragma unroll
    for (int i = 0; i < 4; ++i)
        #pragma unroll
        for (int j = 0; j < 4; ++j)
            acc[i][j] = (f32x4){0.f, 0.f, 0.f, 0.f};

    unsigned rw0, rw1, rz;
    float4   rs0, rs1;
    float4   ra[8];

#define LOADB(TT) do {                                                        \
    const int* bp = qwp + (size_t)(TT) * 64 * NPC;                            \
    rw0 = (unsigned)bp[0]; rw1 = (unsigned)bp[NPC];                           \
    rz  = qzp[(size_t)((TT) >> 1) * NPC];                                     \
    const float* sp = scp + (size_t)((TT) >> 1) * NDIM;                       \
    rs0 = *(const float4*)sp; rs1 = *(const float4*)(sp + 4);                 \
} while (0)

#define LOADA(TT) do {                                                        \
    const float* ap = xp + (size_t)(TT) * 64;                                 \
    ra[0]=*(const float4*)(ap);    ra[1]=*(const float4*)(ap+4);              \
    ra[2]=*(const float4*)(ap+8);  ra[3]=*(const float4*)(ap+12);             \
    ra[4]=*(const float4*)(ap+16); ra[5]=*(const float4*)(ap+20);             \
    ra[6]=*(const float4*)(ap+24); ra[7]=*(const float4*)(ap+28);             \
} while (0)

    LOADB(0);
    if (!XWS) LOADA(0);

    for (int tt = 0; tt < NT; ++tt) {
        __syncthreads();

        if (XWS) {
            const _Float16* img = xi + ((size_t)(mb * NT + tt) * 16384);
            #pragma unroll
            for (int c = 0; c < 4; ++c) {
                __builtin_amdgcn_global_load_lds(
                    (const __attribute__((address_space(1))) void*)
                        (img + c * 4096 + wave * 512 + lane * 8),
                    (__attribute__((address_space(3))) void*)
                        ((char*)As + wave * 1024 + c * 8192),
                    16, 0, 0);
            }
        } else {
            #pragma unroll
            for (int c = 0; c < 2; ++c) {
                const float4 f0 = ra[c * 4 + 0], f1 = ra[c * 4 + 1];
                const float4 f2 = ra[c * 4 + 2], f3 = ra[c * 4 + 3];
                uint4 w0, w1;
                w0.x = pkrtz(f0.x, f0.y); w0.y = pkrtz(f0.z, f0.w);
                w0.z = pkrtz(f1.x, f1.y); w0.w = pkrtz(f1.z, f1.w);
                w1.x = pkrtz(f2.x, f2.y); w1.y = pkrtz(f2.z, f2.w);
                w1.z = pkrtz(f3.x, f3.y); w1.w = pkrtz(f3.z, f3.w);
                const int s0 = (ak >> 3) + c * 2;
                *(uint4*)((char*)As + ar * 128 + ((s0 ^ (ar & 7)) * 16))       = w0;
                *(uint4*)((char*)As + ar * 128 + (((s0 + 1) ^ (ar & 7)) * 16)) = w1;
            }
        }

        {
            unsigned zh[4], sh[4];
            zh[0] = (rz & 0x000F000Fu) | 0x64006400u;
            zh[1] = ((rz >> 4)  & 0x000F000Fu) | 0x64006400u;
            zh[2] = ((rz >> 8)  & 0x000F000Fu) | 0x64006400u;
            zh[3] = ((rz >> 12) & 0x000F000Fu) | 0x64006400u;
            sh[0] = pkrtz(rs0.x, rs0.y); sh[1] = pkrtz(rs0.z, rs0.w);
            sh[2] = pkrtz(rs1.x, rs1.y); sh[3] = pkrtz(rs1.z, rs1.w);
            unsigned dq0[4], dq1[4];
            #pragma unroll
            for (int p = 0; p < 4; ++p) {
                const unsigned q0 = ((rw0 >> (4 * p)) & 0x000F000Fu) | 0x64006400u;
                const unsigned q1 = ((rw1 >> (4 * p)) & 0x000F000Fu) | 0x64006400u;
                dq0[p] = h2u((u2h(q0) - u2h(zh[p])) * u2h(sh[p]));
                dq1[p] = h2u((u2h(q1) - u2h(zh[p])) * u2h(sh[p]));
            }
            const int kslot = bkp >> 2;
            const int ksub  = (bkp & 3) * 4;
            #pragma unroll
            for (int p = 0; p < 4; ++p) {
                const unsigned lo = __builtin_amdgcn_perm(dq1[p], dq0[p], 0x05040100u);
                const unsigned hi = __builtin_amdgcn_perm(dq1[p], dq0[p], 0x07060302u);
                const int ne = bpc * 8 + 2 * p;
                const int no = ne + 1;
                const int swe = (ne & 7) ^ ((ne >> 3) & 7);
                const int swo = (no & 7) ^ ((no >> 3) & 7);
                *(unsigned*)((char*)Bs + ne * 128 + ((kslot ^ swe) * 16) + ksub) = lo;
                *(unsigned*)((char*)Bs + no * 128 + ((kslot ^ swo) * 16) + ksub) = hi;
            }
        }

        __syncthreads();

        if (tt + 1 < NT) { LOADB(tt + 1); if (!XWS) LOADA(tt + 1); }

        #pragma unroll
        for (int ks = 0; ks < 2; ++ks) {
            const int slot = ks * 4 + (lane >> 4);
            half8 bfr[4];
            #pragma unroll
            for (int j = 0; j < 4; ++j) {
                const int n  = WC * 64 + j * 16 + (lane & 15);
                const int sw = (n & 7) ^ ((n >> 3) & 7);
                bfr[j] = *(const half8*)((char*)Bs + n * 128 + ((slot ^ sw) * 16));
            }
            #pragma unroll
            for (int i = 0; i < 4; ++i) {
                const int row = WR * 64 + i * 16 + (lane & 15);
                const half8 af = *(const half8*)((char*)As + row * 128 + ((slot ^ (row & 7)) * 16));
                #pragma unroll
                for (int j = 0; j < 4; ++j)
                    acc[i][j] = __builtin_amdgcn_mfma_f32_16x16x32_f16(
                        af, bfr[j], acc[i][j], 0, 0, 0);
            }
        }
    }

    const int crow = (lane >> 4) * 4;
    const int ccol = lane & 15;
    #pragma unroll
    for (int i = 0; i < 4; ++i) {
        #pragma unroll
        for (int j = 0; j < 4; ++j) {
            const size_t base =
                (size_t)(m0 + WR * 64 + i * 16 + crow) * NDIM +
                (n0 + WC * 64 + j * 16 + ccol);
            #pragma unroll
            for (int e = 0; e < 4; ++e)
                out[base + (size_t)e * NDIM] = acc[i][j][e];
        }
    }
#undef LOADB
#undef LOADA
}

extern "C" void kernel_launch(void* const* d_in, const int* in_sizes, int n_in,
                              void* d_out, int out_size, void* d_ws, size_t ws_size,
                              hipStream_t stream) {
    const float*    x  = (const float*)d_in[0];
    const int*      qw = (const int*)d_in[1];
    const unsigned* qz = (const unsigned*)d_in[2];
    const float*    sc = (const float*)d_in[3];
    float* out = (float*)d_out;

    const size_t XI = (size_t)MDIM * KDIM * 2;          // 16.8 MB f16 x images
    const size_t WI = (size_t)86 * 64 * 16384;          // 90.2 MB f16 W images

    if (ws_size >= XI + WI) {
        _Float16* xi = (_Float16*)d_ws;
        _Float16* wi = (_Float16*)((char*)d_ws + XI);
        xconv128<<<4096, 256, 0, stream>>>(x, xi);
        wdeq<<<dim3(86, 32), 256, 0, stream>>>(qw, qz, sc, wi);
        awq_gemm2<<<dim3(16, 86), 256, 0, stream>>>(xi, wi, out);
    } else if (ws_size >= XI) {
        _Float16* xi = (_Float16*)d_ws;
        xconv256<<<4096, 256, 0, stream>>>(x, xi);
        dim3 grid(NDIM / 128, MDIM / 256);
        awq_fused<true><<<grid, 512, 0, stream>>>(x, xi, qw, qz, sc, out);
    } else {
        dim3 grid(NDIM / 128, MDIM / 256);
        awq_fused<false><<<grid, 512, 0, stream>>>(x, (const _Float16*)nullptr,
                                                   qw, qz, sc, out);
    }
}